// Round 1
// baseline (2057.088 us; speedup 1.0000x reference)
//
#include <hip/hip_runtime.h>
#include <math.h>

#define N_NODES 50000
#define E_EDGES 800000
#define D_DIM 128
#define H_HEADS 2
#define DH_DIM 64
#define C_DIM 256

// ---------------------------------------------------------------------------
// K1: out = x @ W + b for W in {Wq, Wk, Wv, Wskip} (blockIdx.z selects).
// Tiled fp32 GEMM: BM=64, BN=64, BK=16, 256 threads, 4x4 per thread.
// ---------------------------------------------------------------------------
__global__ __launch_bounds__(256) void qkvs_gemm(
    const float* __restrict__ x,
    const float* __restrict__ Wq, const float* __restrict__ bq,
    const float* __restrict__ Wk, const float* __restrict__ bk,
    const float* __restrict__ Wv, const float* __restrict__ bv,
    const float* __restrict__ Wsk, const float* __restrict__ bsk,
    float* __restrict__ qo, float* __restrict__ ko, float* __restrict__ vo,
    float* __restrict__ so)
{
    const float* W; const float* bias; float* out;
    switch (blockIdx.z) {
        case 0: W = Wq;  bias = bq;  out = qo; break;
        case 1: W = Wk;  bias = bk;  out = ko; break;
        case 2: W = Wv;  bias = bv;  out = vo; break;
        default: W = Wsk; bias = bsk; out = so; break;
    }
    __shared__ float As[16][65];   // [k][m], padded
    __shared__ float Bs[16][64];   // [k][n]

    const int tid = threadIdx.x;
    const int tx = tid & 15;       // n-group: cols tx*4..+3
    const int ty = tid >> 4;       // m-group: rows ty*4..+3
    const int m0 = blockIdx.x * 64;
    const int n0 = blockIdx.y * 64;

    const int aRow = tid >> 2;          // 0..63
    const int aCol = (tid & 3) * 4;     // 0,4,8,12
    const int bRow = tid >> 4;          // 0..15
    const int bCol = (tid & 15) * 4;    // 0..60

    float acc[4][4] = {};

    for (int k0 = 0; k0 < 128; k0 += 16) {
        int gm = m0 + aRow;
        float4 av = make_float4(0.f, 0.f, 0.f, 0.f);
        if (gm < N_NODES)
            av = *reinterpret_cast<const float4*>(&x[(size_t)gm * 128 + k0 + aCol]);
        As[aCol + 0][aRow] = av.x;
        As[aCol + 1][aRow] = av.y;
        As[aCol + 2][aRow] = av.z;
        As[aCol + 3][aRow] = av.w;

        *reinterpret_cast<float4*>(&Bs[bRow][bCol]) =
            *reinterpret_cast<const float4*>(&W[(size_t)(k0 + bRow) * 128 + n0 + bCol]);
        __syncthreads();

        #pragma unroll
        for (int kk = 0; kk < 16; ++kk) {
            float rm[4];
            #pragma unroll
            for (int i = 0; i < 4; ++i) rm[i] = As[kk][ty * 4 + i];
            float4 rn = *reinterpret_cast<float4*>(&Bs[kk][tx * 4]);
            #pragma unroll
            for (int i = 0; i < 4; ++i) {
                acc[i][0] += rm[i] * rn.x;
                acc[i][1] += rm[i] * rn.y;
                acc[i][2] += rm[i] * rn.z;
                acc[i][3] += rm[i] * rn.w;
            }
        }
        __syncthreads();
    }

    #pragma unroll
    for (int i = 0; i < 4; ++i) {
        int gm = m0 + ty * 4 + i;
        if (gm >= N_NODES) continue;
        int gn = n0 + tx * 4;
        float4 o;
        o.x = acc[i][0] + bias[gn + 0];
        o.y = acc[i][1] + bias[gn + 1];
        o.z = acc[i][2] + bias[gn + 2];
        o.w = acc[i][3] + bias[gn + 3];
        *reinterpret_cast<float4*>(&out[(size_t)gm * 128 + gn]) = o;
    }
}

// ---------------------------------------------------------------------------
// K2: fused edge pipeline. 32 edges per 256-thread block.
//   e_vec = [cos(rel_t*Wt+bt), msg] @ We         (tiled, We chunks in LDS)
//   alpha = dot(q[dst], k[src]+e_vec)/8 per head (16-lane shuffle reduce)
//   atomicAdd denom[dst,h] += exp(alpha)
//   atomicAdd agg[dst,:]   += exp(alpha) * (v[src]+e_vec)
// Single-pass softmax (no max subtraction: |alpha| <~ 8, exp safe in fp32).
// ---------------------------------------------------------------------------
__global__ __launch_bounds__(256) void edge_kernel(
    const int* __restrict__ ei,
    const float* __restrict__ last_update,
    const float* __restrict__ t,
    const float* __restrict__ msg,
    const float* __restrict__ Wt,
    const float* __restrict__ bt,
    const float* __restrict__ We,
    const float* __restrict__ q,
    const float* __restrict__ k,
    const float* __restrict__ v,
    float* __restrict__ agg,
    float* __restrict__ denom)
{
    __shared__ float sAttr[32][33];    // [c-in-chunk][edge] transposed
    __shared__ float sWe[32][128];     // [c-in-chunk][d]
    __shared__ int   sSrc[32], sDst[32];
    __shared__ float sRelT[32];

    const int tid = threadIdx.x;
    const int e0 = blockIdx.x * 32;

    if (tid < 32) {
        int e = e0 + tid;
        int s = ei[e];
        int dd = ei[E_EDGES + e];
        sSrc[tid] = s;
        sDst[tid] = dd;
        sRelT[tid] = last_update[s] - t[e];
    }
    __syncthreads();

    const int tx = tid & 31;   // d-group: dims tx*4..+3
    const int ty = tid >> 5;   // 0..7 edge-group: edges ty*4..+3

    float acc[4][4] = {};      // e_vec[edge ty*4+i][dim tx*4+j]

    for (int c0 = 0; c0 < 256; c0 += 32) {
        // stage attr chunk (transposed)
        {
            int er = tid >> 3;          // 0..31
            int cc = (tid & 7) * 4;     // 0..28
            if (c0 < 128) {
                float rt = sRelT[er];
                #pragma unroll
                for (int i = 0; i < 4; ++i) {
                    int c = c0 + cc + i;
                    sAttr[cc + i][er] = cosf(rt * Wt[c] + bt[c]);
                }
            } else {
                float4 mv = *reinterpret_cast<const float4*>(
                    &msg[(size_t)(e0 + er) * 128 + (c0 - 128) + cc]);
                sAttr[cc + 0][er] = mv.x;
                sAttr[cc + 1][er] = mv.y;
                sAttr[cc + 2][er] = mv.z;
                sAttr[cc + 3][er] = mv.w;
            }
        }
        // stage We chunk
        {
            int col = (tid & 31) * 4;
            int rbase = tid >> 5;       // 0..7
            #pragma unroll
            for (int i = 0; i < 4; ++i) {
                int row = rbase + i * 8;
                *reinterpret_cast<float4*>(&sWe[row][col]) =
                    *reinterpret_cast<const float4*>(&We[(size_t)(c0 + row) * 128 + col]);
            }
        }
        __syncthreads();

        #pragma unroll
        for (int kc = 0; kc < 32; ++kc) {
            float ra[4];
            #pragma unroll
            for (int i = 0; i < 4; ++i) ra[i] = sAttr[kc][ty * 4 + i];
            float4 rb = *reinterpret_cast<float4*>(&sWe[kc][tx * 4]);
            #pragma unroll
            for (int i = 0; i < 4; ++i) {
                acc[i][0] += ra[i] * rb.x;
                acc[i][1] += ra[i] * rb.y;
                acc[i][2] += ra[i] * rb.z;
                acc[i][3] += ra[i] * rb.w;
            }
        }
        __syncthreads();
    }

    // attention + scatter
    const int h = tx >> 4;     // head of this thread's dims
    float ex[4];
    #pragma unroll
    for (int i = 0; i < 4; ++i) {
        int er = ty * 4 + i;
        int s = sSrc[er], dd = sDst[er];
        float4 qv = *reinterpret_cast<const float4*>(&q[(size_t)dd * 128 + tx * 4]);
        float4 kv = *reinterpret_cast<const float4*>(&k[(size_t)s * 128 + tx * 4]);
        float p = qv.x * (kv.x + acc[i][0]) + qv.y * (kv.y + acc[i][1])
                + qv.z * (kv.z + acc[i][2]) + qv.w * (kv.w + acc[i][3]);
        p += __shfl_xor(p, 1);
        p += __shfl_xor(p, 2);
        p += __shfl_xor(p, 4);
        p += __shfl_xor(p, 8);
        ex[i] = expf(p * 0.125f);   // 1/sqrt(64)
        if ((tx & 15) == 0)
            atomicAdd(&denom[(size_t)dd * 2 + h], ex[i]);
    }

    #pragma unroll
    for (int i = 0; i < 4; ++i) {
        int er = ty * 4 + i;
        int s = sSrc[er], dd = sDst[er];
        float4 vv = *reinterpret_cast<const float4*>(&v[(size_t)s * 128 + tx * 4]);
        float* ap = &agg[(size_t)dd * 128 + tx * 4];
        atomicAdd(ap + 0, ex[i] * (vv.x + acc[i][0]));
        atomicAdd(ap + 1, ex[i] * (vv.y + acc[i][1]));
        atomicAdd(ap + 2, ex[i] * (vv.z + acc[i][2]));
        atomicAdd(ap + 3, ex[i] * (vv.w + acc[i][3]));
    }
}

// ---------------------------------------------------------------------------
// K3: out = agg / denom + skip   (skip already resident in out)
// ---------------------------------------------------------------------------
__global__ __launch_bounds__(256) void finalize(
    const float* __restrict__ agg, const float* __restrict__ denom,
    float* __restrict__ out)
{
    size_t base = ((size_t)blockIdx.x * 256 + threadIdx.x) * 4;
    if (base >= (size_t)N_NODES * 128) return;
    int n = (int)(base >> 7);
    int h = (int)((base >> 6) & 1);
    float dn = denom[(size_t)n * 2 + h];
    float inv = (dn > 0.f) ? (1.f / dn) : 0.f;
    float4 a = *reinterpret_cast<const float4*>(&agg[base]);
    float4 o = *reinterpret_cast<const float4*>(&out[base]);
    o.x += a.x * inv;
    o.y += a.y * inv;
    o.z += a.z * inv;
    o.w += a.w * inv;
    *reinterpret_cast<float4*>(&out[base]) = o;
}

extern "C" void kernel_launch(void* const* d_in, const int* in_sizes, int n_in,
                              void* d_out, int out_size, void* d_ws, size_t ws_size,
                              hipStream_t stream)
{
    const float* x   = (const float*)d_in[0];
    const float* lu  = (const float*)d_in[1];
    const int*   ei  = (const int*)d_in[2];
    const float* t   = (const float*)d_in[3];
    const float* msg = (const float*)d_in[4];
    const float* Wt  = (const float*)d_in[5];
    const float* bt  = (const float*)d_in[6];
    const float* Wq  = (const float*)d_in[7];
    const float* bq  = (const float*)d_in[8];
    const float* Wk  = (const float*)d_in[9];
    const float* bk  = (const float*)d_in[10];
    const float* Wv  = (const float*)d_in[11];
    const float* bv  = (const float*)d_in[12];
    const float* We  = (const float*)d_in[13];
    const float* Wsk = (const float*)d_in[14];
    const float* bsk = (const float*)d_in[15];
    float* out = (float*)d_out;

    float* q   = (float*)d_ws;
    float* k   = q   + (size_t)N_NODES * 128;
    float* v   = k   + (size_t)N_NODES * 128;
    float* agg = v   + (size_t)N_NODES * 128;
    float* den = agg + (size_t)N_NODES * 128;

    // zero agg + denom (contiguous)
    hipMemsetAsync(agg, 0, ((size_t)N_NODES * 128 + (size_t)N_NODES * 2) * sizeof(float),
                   stream);

    dim3 g1((N_NODES + 63) / 64, 2, 4);
    qkvs_gemm<<<g1, 256, 0, stream>>>(x, Wq, bq, Wk, bk, Wv, bv, Wsk, bsk,
                                      q, k, v, out);

    edge_kernel<<<dim3(E_EDGES / 32), 256, 0, stream>>>(
        ei, lu, t, msg, Wt, bt, We, q, k, v, agg, den);

    finalize<<<dim3((N_NODES * 128 / 4 + 255) / 256), 256, 0, stream>>>(agg, den, out);
}

// Round 2
// 1658.756 us; speedup vs baseline: 1.2401x; 1.2401x over previous
//
#include <hip/hip_runtime.h>
#include <math.h>

#define N_NODES 50000
#define E_EDGES 800000
#define D_DIM 128
#define H_HEADS 2
#define DH_DIM 64
#define C_DIM 256

// ---------------------------------------------------------------------------
// K1: out = x @ W + b for W in {Wq, Wk, Wv, Wskip} (blockIdx.z selects).
// Tiled fp32 GEMM: BM=64, BN=64, BK=16, 256 threads, 4x4 per thread.
// ---------------------------------------------------------------------------
__global__ __launch_bounds__(256) void qkvs_gemm(
    const float* __restrict__ x,
    const float* __restrict__ Wq, const float* __restrict__ bq,
    const float* __restrict__ Wk, const float* __restrict__ bk,
    const float* __restrict__ Wv, const float* __restrict__ bv,
    const float* __restrict__ Wsk, const float* __restrict__ bsk,
    float* __restrict__ qo, float* __restrict__ ko, float* __restrict__ vo,
    float* __restrict__ so)
{
    const float* W; const float* bias; float* out;
    switch (blockIdx.z) {
        case 0: W = Wq;  bias = bq;  out = qo; break;
        case 1: W = Wk;  bias = bk;  out = ko; break;
        case 2: W = Wv;  bias = bv;  out = vo; break;
        default: W = Wsk; bias = bsk; out = so; break;
    }
    __shared__ float As[16][65];   // [k][m], padded
    __shared__ float Bs[16][64];   // [k][n]

    const int tid = threadIdx.x;
    const int tx = tid & 15;       // n-group: cols tx*4..+3
    const int ty = tid >> 4;       // m-group: rows ty*4..+3
    const int m0 = blockIdx.x * 64;
    const int n0 = blockIdx.y * 64;

    const int aRow = tid >> 2;          // 0..63
    const int aCol = (tid & 3) * 4;     // 0,4,8,12
    const int bRow = tid >> 4;          // 0..15
    const int bCol = (tid & 15) * 4;    // 0..60

    float acc[4][4] = {};

    for (int k0 = 0; k0 < 128; k0 += 16) {
        int gm = m0 + aRow;
        float4 av = make_float4(0.f, 0.f, 0.f, 0.f);
        if (gm < N_NODES)
            av = *reinterpret_cast<const float4*>(&x[(size_t)gm * 128 + k0 + aCol]);
        As[aCol + 0][aRow] = av.x;
        As[aCol + 1][aRow] = av.y;
        As[aCol + 2][aRow] = av.z;
        As[aCol + 3][aRow] = av.w;

        *reinterpret_cast<float4*>(&Bs[bRow][bCol]) =
            *reinterpret_cast<const float4*>(&W[(size_t)(k0 + bRow) * 128 + n0 + bCol]);
        __syncthreads();

        #pragma unroll
        for (int kk = 0; kk < 16; ++kk) {
            float rm[4];
            #pragma unroll
            for (int i = 0; i < 4; ++i) rm[i] = As[kk][ty * 4 + i];
            float4 rn = *reinterpret_cast<float4*>(&Bs[kk][tx * 4]);
            #pragma unroll
            for (int i = 0; i < 4; ++i) {
                acc[i][0] += rm[i] * rn.x;
                acc[i][1] += rm[i] * rn.y;
                acc[i][2] += rm[i] * rn.z;
                acc[i][3] += rm[i] * rn.w;
            }
        }
        __syncthreads();
    }

    #pragma unroll
    for (int i = 0; i < 4; ++i) {
        int gm = m0 + ty * 4 + i;
        if (gm >= N_NODES) continue;
        int gn = n0 + tx * 4;
        float4 o;
        o.x = acc[i][0] + bias[gn + 0];
        o.y = acc[i][1] + bias[gn + 1];
        o.z = acc[i][2] + bias[gn + 2];
        o.w = acc[i][3] + bias[gn + 3];
        *reinterpret_cast<float4*>(&out[(size_t)gm * 128 + gn]) = o;
    }
}

// ---------------------------------------------------------------------------
// CSR build: histogram of dst -> exclusive scan -> scatter edge ids so that
// `order` lists edges sorted by destination. Rebuilt every call (ws is
// re-poisoned). Cost ~tens of µs; buys temporal locality for the scatter
// atomics in edge_kernel.
// ---------------------------------------------------------------------------
__global__ __launch_bounds__(256) void hist_kernel(
    const int* __restrict__ ei, int* __restrict__ cnt)
{
    int e = blockIdx.x * 256 + threadIdx.x;
    if (e < E_EDGES) atomicAdd(&cnt[ei[E_EDGES + e]], 1);
}

__global__ __launch_bounds__(1024) void scan_kernel(
    const int* __restrict__ cnt, int* __restrict__ cur)
{
    __shared__ int part[1024];
    const int t = threadIdx.x;
    const int CH = (N_NODES + 1023) / 1024;   // 49
    const int base = t * CH;
    int s = 0;
    for (int i = 0; i < CH; ++i) {
        int idx = base + i;
        if (idx < N_NODES) s += cnt[idx];
    }
    part[t] = s;
    __syncthreads();
    int val = s;
    for (int d = 1; d < 1024; d <<= 1) {
        int other = (t >= d) ? part[t - d] : 0;
        __syncthreads();
        val += other;
        part[t] = val;
        __syncthreads();
    }
    int run = val - s;   // exclusive prefix of this thread's chunk
    for (int i = 0; i < CH; ++i) {
        int idx = base + i;
        if (idx < N_NODES) {
            cur[idx] = run;
            run += cnt[idx];
        }
    }
}

__global__ __launch_bounds__(256) void scatter_kernel(
    const int* __restrict__ ei, int* __restrict__ cur, int* __restrict__ order)
{
    int e = blockIdx.x * 256 + threadIdx.x;
    if (e < E_EDGES) {
        int p = atomicAdd(&cur[ei[E_EDGES + e]], 1);
        order[p] = e;
    }
}

// ---------------------------------------------------------------------------
// K2: fused edge pipeline over DST-SORTED edges. 32 edges per 256-thr block.
//   e_vec = [cos(rel_t*Wt+bt), msg] @ We         (tiled, We chunks in LDS)
//   alpha = dot(q[dst], k[src]+e_vec)/8 per head (16-lane shuffle reduce)
//   denom[dst,h] += exp(alpha)   agg[dst,:] += exp(alpha)*(v[src]+e_vec)
// Sorted order => each thread's 4 consecutive edges mostly share dst:
// merge equal-dst runs in registers before the atomic (fewer atomics) and
// adjacent blocks touch adjacent agg lines (atomic RMW stays cache-resident
// instead of thrashing HBM).
// Single-pass softmax (no max subtraction: |alpha| <~ 8, exp safe in fp32).
// ---------------------------------------------------------------------------
__global__ __launch_bounds__(256) void edge_kernel(
    const int* __restrict__ order,
    const int* __restrict__ ei,
    const float* __restrict__ last_update,
    const float* __restrict__ t,
    const float* __restrict__ msg,
    const float* __restrict__ Wt,
    const float* __restrict__ bt,
    const float* __restrict__ We,
    const float* __restrict__ q,
    const float* __restrict__ k,
    const float* __restrict__ v,
    float* __restrict__ agg,
    float* __restrict__ denom)
{
    __shared__ float sAttr[32][33];    // [c-in-chunk][edge] transposed
    __shared__ float sWe[32][128];     // [c-in-chunk][d]
    __shared__ int   sEo[32], sSrc[32], sDst[32];
    __shared__ float sRelT[32];

    const int tid = threadIdx.x;
    const int e0 = blockIdx.x * 32;

    if (tid < 32) {
        int e = order[e0 + tid];
        int s = ei[e];
        int dd = ei[E_EDGES + e];
        sEo[tid] = e;
        sSrc[tid] = s;
        sDst[tid] = dd;
        sRelT[tid] = last_update[s] - t[e];
    }
    __syncthreads();

    const int tx = tid & 31;   // d-group: dims tx*4..+3
    const int ty = tid >> 5;   // 0..7 edge-group: edges ty*4..+3

    float acc[4][4] = {};      // e_vec[edge ty*4+i][dim tx*4+j]

    for (int c0 = 0; c0 < 256; c0 += 32) {
        // stage attr chunk (transposed)
        {
            int er = tid >> 3;          // 0..31
            int cc = (tid & 7) * 4;     // 0..28
            if (c0 < 128) {
                float rt = sRelT[er];
                #pragma unroll
                for (int i = 0; i < 4; ++i) {
                    int c = c0 + cc + i;
                    sAttr[cc + i][er] = cosf(rt * Wt[c] + bt[c]);
                }
            } else {
                float4 mv = *reinterpret_cast<const float4*>(
                    &msg[(size_t)sEo[er] * 128 + (c0 - 128) + cc]);
                sAttr[cc + 0][er] = mv.x;
                sAttr[cc + 1][er] = mv.y;
                sAttr[cc + 2][er] = mv.z;
                sAttr[cc + 3][er] = mv.w;
            }
        }
        // stage We chunk
        {
            int col = (tid & 31) * 4;
            int rbase = tid >> 5;       // 0..7
            #pragma unroll
            for (int i = 0; i < 4; ++i) {
                int row = rbase + i * 8;
                *reinterpret_cast<float4*>(&sWe[row][col]) =
                    *reinterpret_cast<const float4*>(&We[(size_t)(c0 + row) * 128 + col]);
            }
        }
        __syncthreads();

        #pragma unroll
        for (int kc = 0; kc < 32; ++kc) {
            float ra[4];
            #pragma unroll
            for (int i = 0; i < 4; ++i) ra[i] = sAttr[kc][ty * 4 + i];
            float4 rb = *reinterpret_cast<float4*>(&sWe[kc][tx * 4]);
            #pragma unroll
            for (int i = 0; i < 4; ++i) {
                acc[i][0] += ra[i] * rb.x;
                acc[i][1] += ra[i] * rb.y;
                acc[i][2] += ra[i] * rb.z;
                acc[i][3] += ra[i] * rb.w;
            }
        }
        __syncthreads();
    }

    // attention scores
    const int h = tx >> 4;     // head of this thread's dims
    float ex[4];
    #pragma unroll
    for (int i = 0; i < 4; ++i) {
        int er = ty * 4 + i;
        int s = sSrc[er], dd = sDst[er];
        float4 qv = *reinterpret_cast<const float4*>(&q[(size_t)dd * 128 + tx * 4]);
        float4 kv = *reinterpret_cast<const float4*>(&k[(size_t)s * 128 + tx * 4]);
        float p = qv.x * (kv.x + acc[i][0]) + qv.y * (kv.y + acc[i][1])
                + qv.z * (kv.z + acc[i][2]) + qv.w * (kv.w + acc[i][3]);
        p += __shfl_xor(p, 1);
        p += __shfl_xor(p, 2);
        p += __shfl_xor(p, 4);
        p += __shfl_xor(p, 8);
        ex[i] = expf(p * 0.125f);   // 1/sqrt(64)
    }

    // denom: merge equal-dst runs in registers, one atomic per run
    if ((tx & 15) == 0) {
        float dsum = ex[0];
        #pragma unroll
        for (int i = 1; i < 4; ++i) {
            int er = ty * 4 + i;
            if (sDst[er] == sDst[er - 1]) {
                dsum += ex[i];
            } else {
                atomicAdd(&denom[(size_t)sDst[er - 1] * 2 + h], dsum);
                dsum = ex[i];
            }
        }
        atomicAdd(&denom[(size_t)sDst[ty * 4 + 3] * 2 + h], dsum);
    }

    // values: merge equal-dst runs, one 4-float atomic row per run
    float4 run;
    int prevDst = sDst[ty * 4];
    #pragma unroll
    for (int i = 0; i < 4; ++i) {
        int er = ty * 4 + i;
        int s = sSrc[er], dd = sDst[er];
        float4 vv = *reinterpret_cast<const float4*>(&v[(size_t)s * 128 + tx * 4]);
        float4 cur;
        cur.x = ex[i] * (vv.x + acc[i][0]);
        cur.y = ex[i] * (vv.y + acc[i][1]);
        cur.z = ex[i] * (vv.z + acc[i][2]);
        cur.w = ex[i] * (vv.w + acc[i][3]);
        if (i == 0) {
            run = cur;
        } else if (dd == prevDst) {
            run.x += cur.x; run.y += cur.y; run.z += cur.z; run.w += cur.w;
        } else {
            float* ap = &agg[(size_t)prevDst * 128 + tx * 4];
            atomicAdd(ap + 0, run.x);
            atomicAdd(ap + 1, run.y);
            atomicAdd(ap + 2, run.z);
            atomicAdd(ap + 3, run.w);
            run = cur;
            prevDst = dd;
        }
    }
    {
        float* ap = &agg[(size_t)prevDst * 128 + tx * 4];
        atomicAdd(ap + 0, run.x);
        atomicAdd(ap + 1, run.y);
        atomicAdd(ap + 2, run.z);
        atomicAdd(ap + 3, run.w);
    }
}

// ---------------------------------------------------------------------------
// K3: out = agg / denom + skip   (skip already resident in out)
// ---------------------------------------------------------------------------
__global__ __launch_bounds__(256) void finalize(
    const float* __restrict__ agg, const float* __restrict__ denom,
    float* __restrict__ out)
{
    size_t base = ((size_t)blockIdx.x * 256 + threadIdx.x) * 4;
    if (base >= (size_t)N_NODES * 128) return;
    int n = (int)(base >> 7);
    int h = (int)((base >> 6) & 1);
    float dn = denom[(size_t)n * 2 + h];
    float inv = (dn > 0.f) ? (1.f / dn) : 0.f;
    float4 a = *reinterpret_cast<const float4*>(&agg[base]);
    float4 o = *reinterpret_cast<const float4*>(&out[base]);
    o.x += a.x * inv;
    o.y += a.y * inv;
    o.z += a.z * inv;
    o.w += a.w * inv;
    *reinterpret_cast<float4*>(&out[base]) = o;
}

extern "C" void kernel_launch(void* const* d_in, const int* in_sizes, int n_in,
                              void* d_out, int out_size, void* d_ws, size_t ws_size,
                              hipStream_t stream)
{
    const float* x   = (const float*)d_in[0];
    const float* lu  = (const float*)d_in[1];
    const int*   ei  = (const int*)d_in[2];
    const float* t   = (const float*)d_in[3];
    const float* msg = (const float*)d_in[4];
    const float* Wt  = (const float*)d_in[5];
    const float* bt  = (const float*)d_in[6];
    const float* Wq  = (const float*)d_in[7];
    const float* bq  = (const float*)d_in[8];
    const float* Wk  = (const float*)d_in[9];
    const float* bk  = (const float*)d_in[10];
    const float* Wv  = (const float*)d_in[11];
    const float* bv  = (const float*)d_in[12];
    const float* We  = (const float*)d_in[13];
    const float* Wsk = (const float*)d_in[14];
    const float* bsk = (const float*)d_in[15];
    float* out = (float*)d_out;

    float* q    = (float*)d_ws;
    float* k    = q   + (size_t)N_NODES * 128;
    float* v    = k   + (size_t)N_NODES * 128;
    float* agg  = v   + (size_t)N_NODES * 128;
    float* den  = agg + (size_t)N_NODES * 128;
    int*   cnt  = (int*)(den + (size_t)N_NODES * 2);
    int*   cur  = cnt + N_NODES;
    int*   order= cur + N_NODES;

    // zero agg + denom + cnt (contiguous)
    hipMemsetAsync(agg, 0,
                   ((size_t)N_NODES * 128 + (size_t)N_NODES * 2 + N_NODES) * sizeof(float),
                   stream);

    dim3 g1((N_NODES + 63) / 64, 2, 4);
    qkvs_gemm<<<g1, 256, 0, stream>>>(x, Wq, bq, Wk, bk, Wv, bv, Wsk, bsk,
                                      q, k, v, out);

    hist_kernel<<<dim3((E_EDGES + 255) / 256), 256, 0, stream>>>(ei, cnt);
    scan_kernel<<<dim3(1), 1024, 0, stream>>>(cnt, cur);
    scatter_kernel<<<dim3((E_EDGES + 255) / 256), 256, 0, stream>>>(ei, cur, order);

    edge_kernel<<<dim3(E_EDGES / 32), 256, 0, stream>>>(
        order, ei, lu, t, msg, Wt, bt, We, q, k, v, agg, den);

    finalize<<<dim3((N_NODES * 128 / 4 + 255) / 256), 256, 0, stream>>>(agg, den, out);
}